// Round 1
// baseline (1933.732 us; speedup 1.0000x reference)
//
#include <hip/hip_runtime.h>
#include <math.h>

// ---------------- float <-> monotone uint key (for atomicMax on float) ------
__device__ __forceinline__ unsigned fkey(float f) {
    unsigned u = __float_as_uint(f);
    return (u & 0x80000000u) ? ~u : (u | 0x80000000u);
}
__device__ __forceinline__ float funkey(unsigned k) {
    return __uint_as_float((k & 0x80000000u) ? (k & 0x7FFFFFFFu) : ~k);
}

// Load an edge index that may be int32 or int64 (little-endian) -------------
__device__ __forceinline__ int ldidx(const void* ei, int pos, bool i64) {
    if (i64) return (int)((const long long*)ei)[pos];
    return ((const int*)ei)[pos];
}

// ---------------- dtype detection: int64 edge_index has zero high words -----
__global__ void detect_i64(const unsigned* ei32, int* flag) {
    __shared__ int nz;
    if (threadIdx.x == 0) nz = 0;
    __syncthreads();
    unsigned v = ei32[2 * threadIdx.x + 1];   // odd int32 slots
    if (v != 0) atomicOr(&nz, 1);
    __syncthreads();
    if (threadIdx.x == 0) *flag = (nz == 0) ? 1 : 0;  // all zero -> int64
}

// ---------------- layer 1 GEMM: xp1 = x @ W1, plus alpha_s/alpha_d ---------
// block 256 = 2 rows x 128 threads; thread c computes output channel c.
__global__ void gemm1(const float* __restrict__ x, const float* __restrict__ W1,
                      const float* __restrict__ aw_s, const float* __restrict__ aw_d,
                      float* __restrict__ xp, float* __restrict__ as1,
                      float* __restrict__ ad1, int n) {
    __shared__ float xs[2][128];
    int t = threadIdx.x;
    int r = t >> 7;           // 0/1
    int c = t & 127;
    int row = blockIdx.x * 2 + r;
    if (row < n) xs[r][c] = x[(size_t)row * 128 + c];
    __syncthreads();
    if (row >= n) return;
    float acc = 0.f;
#pragma unroll 8
    for (int k = 0; k < 128; ++k)
        acc = fmaf(xs[r][k], W1[k * 128 + c], acc);
    xp[(size_t)row * 128 + c] = acc;
    int h = c >> 5, lc = c & 31;
    float ps = acc * aw_s[h * 32 + lc];
    float pd = acc * aw_d[h * 32 + lc];
    for (int off = 16; off >= 1; off >>= 1) {
        ps += __shfl_xor(ps, off, 32);
        pd += __shfl_xor(pd, off, 32);
    }
    if (lc == 0) { as1[row * 4 + h] = ps; ad1[row * 4 + h] = pd; }
}

// ---------------- layer 1 edge pass A: e = lrelu(as[src]+ad[dst]); seg-max --
__global__ void edgeA4(const void* ei, const int* dflag,
                       const float* __restrict__ as1, const float* __restrict__ ad1,
                       float* __restrict__ e_out, unsigned* __restrict__ mmax,
                       int E, int Etot) {
    int i = blockIdx.x * blockDim.x + threadIdx.x;
    if (i >= Etot * 4) return;
    bool i64 = (*dflag != 0);
    int eid = i >> 2, h = i & 3;
    int s, d;
    if (eid < E) { s = ldidx(ei, eid, i64); d = ldidx(ei, E + eid, i64); }
    else         { s = d = eid - E; }
    float e = as1[s * 4 + h] + ad1[d * 4 + h];
    e = e > 0.f ? e : 0.2f * e;
    e_out[i] = e;
    atomicMax(&mmax[d * 4 + h], fkey(e));
}

// ---------------- layer 1 edge pass B: ex = exp(e - m[dst]); seg-sum -------
__global__ void edgeB4(const void* ei, const int* dflag,
                       const unsigned* __restrict__ mmax, float* __restrict__ e_buf,
                       float* __restrict__ denom, int E, int Etot) {
    int i = blockIdx.x * blockDim.x + threadIdx.x;
    if (i >= Etot * 4) return;
    bool i64 = (*dflag != 0);
    int eid = i >> 2, h = i & 3;
    int d = (eid < E) ? ldidx(ei, E + eid, i64) : eid - E;
    float m = funkey(mmax[d * 4 + h]);
    float ex = expf(e_buf[i] - m);
    e_buf[i] = ex;
    unsafeAtomicAdd(&denom[d * 4 + h], ex);
}

// ---------------- layer 1 edge pass C: out[dst] += xp[src] * alpha ---------
// half-wave (32 lanes) per edge, float4 per lane -> 512B row.
__global__ void edgeC4(const void* ei, const int* dflag,
                       const float* __restrict__ xp, const float* __restrict__ exb,
                       const float* __restrict__ denom, float* __restrict__ outa,
                       int E, int Etot) {
    long long gid = (long long)blockIdx.x * blockDim.x + threadIdx.x;
    int eid = (int)(gid >> 5);
    if (eid >= Etot) return;
    bool i64 = (*dflag != 0);
    int lane = (int)(gid & 31);
    int s, d;
    if (eid < E) { s = ldidx(ei, eid, i64); d = ldidx(ei, E + eid, i64); }
    else         { s = d = eid - E; }
    int h = lane >> 3;                       // 8 lanes (32 ch) per head
    float alpha = exb[eid * 4 + h] / denom[d * 4 + h];
    const float4 v = *(const float4*)(xp + (size_t)s * 128 + lane * 4);
    float* o = outa + (size_t)d * 128 + lane * 4;
    unsafeAtomicAdd(o + 0, v.x * alpha);
    unsafeAtomicAdd(o + 1, v.y * alpha);
    unsafeAtomicAdd(o + 2, v.z * alpha);
    unsafeAtomicAdd(o + 3, v.w * alpha);
}

// ---------------- node epilogue L1 + layer 2 projection --------------------
// h = elu(acc + b1); xp2 = h @ W2; alpha_s2/alpha_d2.
// block 256 = 16 nodes x 16 threads.
__global__ void node1(const float* __restrict__ acc1, const float* __restrict__ b1,
                      const float* __restrict__ W2, const float* __restrict__ aw_s,
                      const float* __restrict__ aw_d, float* __restrict__ xp2,
                      float* __restrict__ as2, float* __restrict__ ad2, int n) {
    __shared__ float hs[16][128];
    int t = threadIdx.x;
    int ln = t >> 4;
    int j = t & 15;
    int node = blockIdx.x * 16 + ln;
    if (node < n) {
#pragma unroll
        for (int q = 0; q < 8; ++q) {
            int c = j * 8 + q;
            float hv = acc1[(size_t)node * 128 + c] + b1[c];
            hs[ln][c] = hv > 0.f ? hv : expm1f(hv);
        }
    }
    __syncthreads();
    if (node >= n) return;
    float acc = 0.f;
#pragma unroll 4
    for (int c = 0; c < 128; ++c)
        acc = fmaf(hs[ln][c], W2[c * 16 + j], acc);
    xp2[(size_t)node * 16 + j] = acc;
    float ps = acc * aw_s[j];
    float pd = acc * aw_d[j];
    for (int off = 8; off >= 1; off >>= 1) {
        ps += __shfl_xor(ps, off, 16);
        pd += __shfl_xor(pd, off, 16);
    }
    if (j == 0) { as2[node] = ps; ad2[node] = pd; }
}

// ---------------- layer 2 edge passes (1 head, 16 ch) ----------------------
__global__ void edgeA1(const void* ei, const int* dflag,
                       const float* __restrict__ as2, const float* __restrict__ ad2,
                       float* __restrict__ e_out, unsigned* __restrict__ mmax,
                       int E, int Etot) {
    int i = blockIdx.x * blockDim.x + threadIdx.x;
    if (i >= Etot) return;
    bool i64 = (*dflag != 0);
    int s, d;
    if (i < E) { s = ldidx(ei, i, i64); d = ldidx(ei, E + i, i64); }
    else       { s = d = i - E; }
    float e = as2[s] + ad2[d];
    e = e > 0.f ? e : 0.2f * e;
    e_out[i] = e;
    atomicMax(&mmax[d], fkey(e));
}

__global__ void edgeB1(const void* ei, const int* dflag,
                       const unsigned* __restrict__ mmax, float* __restrict__ e_buf,
                       float* __restrict__ denom, int E, int Etot) {
    int i = blockIdx.x * blockDim.x + threadIdx.x;
    if (i >= Etot) return;
    bool i64 = (*dflag != 0);
    int d = (i < E) ? ldidx(ei, E + i, i64) : i - E;
    float ex = expf(e_buf[i] - funkey(mmax[d]));
    e_buf[i] = ex;
    unsafeAtomicAdd(&denom[d], ex);
}

// 4 lanes per edge, float4 each -> 16 channels.
__global__ void edgeC1(const void* ei, const int* dflag,
                       const float* __restrict__ xp2, const float* __restrict__ exb,
                       const float* __restrict__ denom, float* __restrict__ outa,
                       int E, int Etot) {
    long long gid = (long long)blockIdx.x * blockDim.x + threadIdx.x;
    int eid = (int)(gid >> 2);
    if (eid >= Etot) return;
    bool i64 = (*dflag != 0);
    int lane = (int)(gid & 3);
    int s, d;
    if (eid < E) { s = ldidx(ei, eid, i64); d = ldidx(ei, E + eid, i64); }
    else         { s = d = eid - E; }
    float alpha = exb[eid] / denom[d];
    const float4 v = *(const float4*)(xp2 + (size_t)s * 16 + lane * 4);
    float* o = outa + (size_t)d * 16 + lane * 4;
    unsafeAtomicAdd(o + 0, v.x * alpha);
    unsafeAtomicAdd(o + 1, v.y * alpha);
    unsafeAtomicAdd(o + 2, v.z * alpha);
    unsafeAtomicAdd(o + 3, v.w * alpha);
}

// ---------------- final: +b2, log_softmax over 16 channels -----------------
__global__ void finalk(const float* __restrict__ out2a, const float* __restrict__ b2,
                       float* __restrict__ out, int n) {
    int t = threadIdx.x;
    int node = blockIdx.x * 16 + (t >> 4);
    int j = t & 15;
    if (node >= n) return;
    float v = out2a[(size_t)node * 16 + j] + b2[j];
    float m = v;
    for (int off = 8; off >= 1; off >>= 1) m = fmaxf(m, __shfl_xor(m, off, 16));
    float ex = expf(v - m);
    float s = ex;
    for (int off = 8; off >= 1; off >>= 1) s += __shfl_xor(s, off, 16);
    out[(size_t)node * 16 + j] = v - m - logf(s);
}

// ---------------------------------------------------------------------------
extern "C" void kernel_launch(void* const* d_in, const int* in_sizes, int n_in,
                              void* d_out, int out_size, void* d_ws, size_t ws_size,
                              hipStream_t stream) {
    const float* x    = (const float*)d_in[0];
    const void*  ei   = d_in[1];
    const float* W1   = (const float*)d_in[2];
    const float* aS1  = (const float*)d_in[3];
    const float* aD1  = (const float*)d_in[4];
    const float* b1   = (const float*)d_in[5];
    const float* W2   = (const float*)d_in[6];
    const float* aS2  = (const float*)d_in[7];
    const float* aD2  = (const float*)d_in[8];
    const float* b2   = (const float*)d_in[9];

    const int N    = in_sizes[0] / 128;
    const int E    = in_sizes[1] / 2;
    const int Etot = E + N;

    // ---- workspace layout (floats) ----
    float* ws   = (float*)d_ws;
    float* xp1  = ws;                              // 128N
    float* as1  = xp1 + (size_t)128 * N;           // 4N
    float* ad1  = as1 + (size_t)4 * N;             // 4N
    float* e1   = ad1 + (size_t)4 * N;             // 4*Etot
    float* zone = e1 + (size_t)4 * Etot;           // ---- zeroed zone start
    unsigned* m1   = (unsigned*)zone;              // 4N
    float*    den1 = zone + (size_t)4 * N;         // 4N
    float*    acc1 = den1 + (size_t)4 * N;         // 128N
    unsigned* m2   = (unsigned*)(acc1 + (size_t)128 * N); // N
    float*    den2 = (float*)m2 + N;               // N
    float*    o2a  = den2 + N;                     // 16N
    float* zend = o2a + (size_t)16 * N;            // ---- zeroed zone end
    float* xp2  = zend;                            // 16N
    float* as2  = xp2 + (size_t)16 * N;            // N
    float* ad2  = as2 + N;                         // N
    float* e2   = ad2 + N;                         // Etot
    int*   dflag = (int*)(e2 + Etot);              // 1

    hipMemsetAsync(zone, 0, (char*)zend - (char*)zone, stream);

    detect_i64<<<1, 256, 0, stream>>>((const unsigned*)ei, dflag);

    gemm1<<<(N + 1) / 2, 256, 0, stream>>>(x, W1, aS1, aD1, xp1, as1, ad1, N);

    int tA = Etot * 4;
    edgeA4<<<(tA + 255) / 256, 256, 0, stream>>>(ei, dflag, as1, ad1, e1, m1, E, Etot);
    edgeB4<<<(tA + 255) / 256, 256, 0, stream>>>(ei, dflag, m1, e1, den1, E, Etot);
    edgeC4<<<(int)(((long long)Etot * 32 + 255) / 256), 256, 0, stream>>>(
        ei, dflag, xp1, e1, den1, acc1, E, Etot);

    node1<<<(N + 15) / 16, 256, 0, stream>>>(acc1, b1, W2, aS2, aD2, xp2, as2, ad2, N);

    edgeA1<<<(Etot + 255) / 256, 256, 0, stream>>>(ei, dflag, as2, ad2, e2, m2, E, Etot);
    edgeB1<<<(Etot + 255) / 256, 256, 0, stream>>>(ei, dflag, m2, e2, den2, E, Etot);
    edgeC1<<<(int)(((long long)Etot * 4 + 255) / 256), 256, 0, stream>>>(
        ei, dflag, xp2, e2, den2, o2a, E, Etot);

    finalk<<<(N + 15) / 16, 256, 0, stream>>>(o2a, b2, (float*)d_out, N);
}

// Round 2
// 443.673 us; speedup vs baseline: 4.3585x; 4.3585x over previous
//
#include <hip/hip_runtime.h>
#include <math.h>

// Load an edge index that may be int32 or int64 (little-endian) -------------
__device__ __forceinline__ int ldidx(const void* ei, int pos, bool i64) {
    if (i64) return (int)((const long long*)ei)[pos];
    return ((const int*)ei)[pos];
}

// ---------------- dtype detection: int64 edge_index has zero high words -----
__global__ void detect_i64(const unsigned* ei32, int* flag) {
    __shared__ int nz;
    if (threadIdx.x == 0) nz = 0;
    __syncthreads();
    unsigned v = ei32[2 * threadIdx.x + 1];   // odd int32 slots
    if (v != 0) atomicOr(&nz, 1);
    __syncthreads();
    if (threadIdx.x == 0) *flag = (nz == 0) ? 1 : 0;  // all zero -> int64
}

// ---------------- layer 1 GEMM: xp1 = x @ W1, plus alpha_s/alpha_d ---------
__global__ void gemm1(const float* __restrict__ x, const float* __restrict__ W1,
                      const float* __restrict__ aw_s, const float* __restrict__ aw_d,
                      float* __restrict__ xp, float* __restrict__ as1,
                      float* __restrict__ ad1, int n) {
    __shared__ float xs[2][128];
    int t = threadIdx.x;
    int r = t >> 7;
    int c = t & 127;
    int row = blockIdx.x * 2 + r;
    if (row < n) xs[r][c] = x[(size_t)row * 128 + c];
    __syncthreads();
    if (row >= n) return;
    float acc = 0.f;
#pragma unroll 8
    for (int k = 0; k < 128; ++k)
        acc = fmaf(xs[r][k], W1[k * 128 + c], acc);
    xp[(size_t)row * 128 + c] = acc;
    int h = c >> 5, lc = c & 31;
    float ps = acc * aw_s[h * 32 + lc];
    float pd = acc * aw_d[h * 32 + lc];
    for (int off = 16; off >= 1; off >>= 1) {
        ps += __shfl_xor(ps, off, 32);
        pd += __shfl_xor(pd, off, 32);
    }
    if (lc == 0) { as1[row * 4 + h] = ps; ad1[row * 4 + h] = pd; }
}

// ---------------- CSR build: histogram of dst ------------------------------
__global__ void hist_k(const void* ei, const int* dflag, int* cnt, int E, int Etot) {
    int i = blockIdx.x * blockDim.x + threadIdx.x;
    if (i >= Etot) return;
    bool i64 = (*dflag != 0);
    int d = (i < E) ? ldidx(ei, E + i, i64) : i - E;
    atomicAdd(&cnt[d], 1);
}

// ---------------- CSR build: single-block exclusive scan -------------------
__global__ void scan_k(const int* __restrict__ cnt, int* __restrict__ rp,
                       int* __restrict__ cur, int n) {
    __shared__ int part[1024];
    int t = threadIdx.x;
    int K = (n + 1023) / 1024;
    int lo = t * K;
    int hi = lo + K; if (hi > n) hi = n; if (lo > n) lo = n;
    int s = 0;
    for (int i = lo; i < hi; ++i) s += cnt[i];
    part[t] = s;
    __syncthreads();
    for (int off = 1; off < 1024; off <<= 1) {
        int v = (t >= off) ? part[t - off] : 0;
        __syncthreads();
        part[t] += v;
        __syncthreads();
    }
    int run = (t == 0) ? 0 : part[t - 1];
    for (int i = lo; i < hi; ++i) {
        rp[i] = run; cur[i] = run;
        run += cnt[i];
    }
    if (t == 1023) rp[n] = run;
}

// ---------------- CSR build: scatter src ids into position -----------------
__global__ void scatter_k(const void* ei, const int* dflag, int* cur,
                          int* src_csr, int E, int Etot) {
    int i = blockIdx.x * blockDim.x + threadIdx.x;
    if (i >= Etot) return;
    bool i64 = (*dflag != 0);
    int s, d;
    if (i < E) { s = ldidx(ei, i, i64); d = ldidx(ei, E + i, i64); }
    else       { s = d = i - E; }
    int pos = atomicAdd(&cur[d], 1);
    src_csr[pos] = s;
}

// ---------------- layer 1 aggregation: gather, softmax, +b1, ELU -----------
// 32 lanes per dst node; lane holds channels [lane*4, lane*4+4); head = lane>>3.
__global__ void agg1(const int* __restrict__ rp, const int* __restrict__ src_csr,
                     const float* __restrict__ as1, const float* __restrict__ ad1,
                     const float* __restrict__ xp, const float* __restrict__ b1,
                     float* __restrict__ hout, int n) {
    int g = blockIdx.x * 8 + (threadIdx.x >> 5);
    if (g >= n) return;
    int lane = threadIdx.x & 31;
    int h = lane >> 3;
    int beg = rp[g], end = rp[g + 1];
    float adv = ad1[g * 4 + h];
    float m = -INFINITY;
    for (int j = beg; j < end; ++j) {
        int s = src_csr[j];
        float e = as1[s * 4 + h] + adv;
        e = e > 0.f ? e : 0.2f * e;
        m = fmaxf(m, e);
    }
    float ax = 0.f, ay = 0.f, az = 0.f, aw = 0.f, den = 0.f;
    for (int j = beg; j < end; ++j) {
        int s = src_csr[j];
        float e = as1[s * 4 + h] + adv;
        e = e > 0.f ? e : 0.2f * e;
        float ex = expf(e - m);
        den += ex;
        const float4 v = *(const float4*)(xp + (size_t)s * 128 + lane * 4);
        ax = fmaf(v.x, ex, ax); ay = fmaf(v.y, ex, ay);
        az = fmaf(v.z, ex, az); aw = fmaf(v.w, ex, aw);
    }
    float inv = 1.f / den;
    int c0 = lane * 4;
    const float4 bb = *(const float4*)(b1 + c0);
    float o0 = fmaf(ax, inv, bb.x); o0 = o0 > 0.f ? o0 : expm1f(o0);
    float o1 = fmaf(ay, inv, bb.y); o1 = o1 > 0.f ? o1 : expm1f(o1);
    float o2 = fmaf(az, inv, bb.z); o2 = o2 > 0.f ? o2 : expm1f(o2);
    float o3 = fmaf(aw, inv, bb.w); o3 = o3 > 0.f ? o3 : expm1f(o3);
    float4 o = {o0, o1, o2, o3};
    *(float4*)(hout + (size_t)g * 128 + c0) = o;
}

// ---------------- layer 2 projection: xp2 = h @ W2, alpha_s2/alpha_d2 ------
__global__ void proj2(const float* __restrict__ h, const float* __restrict__ W2,
                      const float* __restrict__ aw_s, const float* __restrict__ aw_d,
                      float* __restrict__ xp2, float* __restrict__ as2,
                      float* __restrict__ ad2, int n) {
    __shared__ float hs[16][128];
    int t = threadIdx.x;
    int ln = t >> 4;
    int j = t & 15;
    int node = blockIdx.x * 16 + ln;
    if (node < n) {
#pragma unroll
        for (int q = 0; q < 8; ++q) {
            int c = j * 8 + q;
            hs[ln][c] = h[(size_t)node * 128 + c];
        }
    }
    __syncthreads();
    if (node >= n) return;
    float acc = 0.f;
#pragma unroll 4
    for (int c = 0; c < 128; ++c)
        acc = fmaf(hs[ln][c], W2[c * 16 + j], acc);
    xp2[(size_t)node * 16 + j] = acc;
    float ps = acc * aw_s[j];
    float pd = acc * aw_d[j];
    for (int off = 8; off >= 1; off >>= 1) {
        ps += __shfl_xor(ps, off, 16);
        pd += __shfl_xor(pd, off, 16);
    }
    if (j == 0) { as2[node] = ps; ad2[node] = pd; }
}

// ---------------- layer 2 aggregation + bias + log_softmax -----------------
// 4 lanes per dst node; lane holds channels [lane*4, lane*4+4).
__global__ void agg2(const int* __restrict__ rp, const int* __restrict__ src_csr,
                     const float* __restrict__ as2, const float* __restrict__ ad2,
                     const float* __restrict__ xp2, const float* __restrict__ b2,
                     float* __restrict__ out, int n) {
    int g = blockIdx.x * 64 + (threadIdx.x >> 2);
    if (g >= n) return;
    int lane = threadIdx.x & 3;
    int beg = rp[g], end = rp[g + 1];
    float adv = ad2[g];
    float m = -INFINITY;
    for (int j = beg; j < end; ++j) {
        float e = as2[src_csr[j]] + adv;
        e = e > 0.f ? e : 0.2f * e;
        m = fmaxf(m, e);
    }
    float ax = 0.f, ay = 0.f, az = 0.f, aw = 0.f, den = 0.f;
    for (int j = beg; j < end; ++j) {
        int s = src_csr[j];
        float e = as2[s] + adv;
        e = e > 0.f ? e : 0.2f * e;
        float ex = expf(e - m);
        den += ex;
        const float4 v = *(const float4*)(xp2 + (size_t)s * 16 + lane * 4);
        ax = fmaf(v.x, ex, ax); ay = fmaf(v.y, ex, ay);
        az = fmaf(v.z, ex, az); aw = fmaf(v.w, ex, aw);
    }
    float inv = 1.f / den;
    const float4 bb = *(const float4*)(b2 + lane * 4);
    float v0 = fmaf(ax, inv, bb.x);
    float v1 = fmaf(ay, inv, bb.y);
    float v2 = fmaf(az, inv, bb.z);
    float v3 = fmaf(aw, inv, bb.w);
    float mm = fmaxf(fmaxf(v0, v1), fmaxf(v2, v3));
    for (int off = 1; off < 4; off <<= 1) mm = fmaxf(mm, __shfl_xor(mm, off, 4));
    float ss = expf(v0 - mm) + expf(v1 - mm) + expf(v2 - mm) + expf(v3 - mm);
    for (int off = 1; off < 4; off <<= 1) ss += __shfl_xor(ss, off, 4);
    float ls = mm + logf(ss);
    float4 o = {v0 - ls, v1 - ls, v2 - ls, v3 - ls};
    *(float4*)(out + (size_t)g * 16 + lane * 4) = o;
}

// ---------------------------------------------------------------------------
extern "C" void kernel_launch(void* const* d_in, const int* in_sizes, int n_in,
                              void* d_out, int out_size, void* d_ws, size_t ws_size,
                              hipStream_t stream) {
    const float* x    = (const float*)d_in[0];
    const void*  ei   = d_in[1];
    const float* W1   = (const float*)d_in[2];
    const float* aS1  = (const float*)d_in[3];
    const float* aD1  = (const float*)d_in[4];
    const float* b1   = (const float*)d_in[5];
    const float* W2   = (const float*)d_in[6];
    const float* aS2  = (const float*)d_in[7];
    const float* aD2  = (const float*)d_in[8];
    const float* b2   = (const float*)d_in[9];

    const int N    = in_sizes[0] / 128;
    const int E    = in_sizes[1] / 2;
    const int Etot = E + N;

    // ---- workspace layout ----
    float* ws   = (float*)d_ws;
    float* xp1  = ws;                               // 128N
    float* as1  = xp1 + (size_t)128 * N;            // 4N
    float* ad1  = as1 + (size_t)4 * N;              // 4N
    float* hbuf = ad1 + (size_t)4 * N;              // 128N
    float* xp2  = hbuf + (size_t)128 * N;           // 16N
    float* as2  = xp2 + (size_t)16 * N;             // N
    float* ad2  = as2 + N;                          // N
    int*   cnt  = (int*)(ad2 + N);                  // N  (zeroed)
    int*   rp   = cnt + N;                          // N+1
    int*   cur  = rp + N + 1;                       // N
    int*   src_csr = cur + N;                       // Etot
    int*   dflag   = src_csr + Etot;                // 1

    hipMemsetAsync(cnt, 0, (size_t)N * sizeof(int), stream);

    detect_i64<<<1, 256, 0, stream>>>((const unsigned*)ei, dflag);

    gemm1<<<(N + 1) / 2, 256, 0, stream>>>(x, W1, aS1, aD1, xp1, as1, ad1, N);

    hist_k<<<(Etot + 255) / 256, 256, 0, stream>>>(ei, dflag, cnt, E, Etot);
    scan_k<<<1, 1024, 0, stream>>>(cnt, rp, cur, N);
    scatter_k<<<(Etot + 255) / 256, 256, 0, stream>>>(ei, dflag, cur, src_csr, E, Etot);

    agg1<<<(N + 7) / 8, 256, 0, stream>>>(rp, src_csr, as1, ad1, xp1, b1, hbuf, N);

    proj2<<<(N + 15) / 16, 256, 0, stream>>>(hbuf, W2, aS2, aD2, xp2, as2, ad2, N);

    agg2<<<(N + 63) / 64, 256, 0, stream>>>(rp, src_csr, as2, ad2, xp2, b2,
                                            (float*)d_out, N);
}

// Round 3
// 379.963 us; speedup vs baseline: 5.0893x; 1.1677x over previous
//
#include <hip/hip_runtime.h>
#include <math.h>

typedef __attribute__((ext_vector_type(4))) float f32x4;
typedef __attribute__((ext_vector_type(8))) short s16x8;

// ---------------- bf16 helpers ---------------------------------------------
__device__ __forceinline__ unsigned short f2bf(float f) {
    unsigned u = __float_as_uint(f);
    unsigned r = u + 0x7FFFu + ((u >> 16) & 1u);   // round-to-nearest-even
    return (unsigned short)(r >> 16);
}
__device__ __forceinline__ float bf2f(unsigned short b) {
    return __uint_as_float(((unsigned)b) << 16);
}

// Load an edge index that may be int32 or int64 (little-endian) -------------
__device__ __forceinline__ int ldidx(const void* ei, int pos, bool i64) {
    if (i64) return (int)((const long long*)ei)[pos];
    return ((const int*)ei)[pos];
}

// ---------------- dtype detection: int64 edge_index has zero high words -----
__global__ void detect_i64(const unsigned* ei32, int* flag) {
    __shared__ int nz;
    if (threadIdx.x == 0) nz = 0;
    __syncthreads();
    unsigned v = ei32[2 * threadIdx.x + 1];
    if (v != 0) atomicOr(&nz, 1);
    __syncthreads();
    if (threadIdx.x == 0) *flag = (nz == 0) ? 1 : 0;
}

// ---------------- prep: Bt[144][128] = [W1 | Ws | Wd]^T in bf16 ------------
// Ws[:,h] = sum_c W1[:,h*32+c]*a_src[h,c]; rows 136..143 zero padding.
__global__ void prep_bt(const float* __restrict__ W1, const float* __restrict__ aS,
                        const float* __restrict__ aD, unsigned short* __restrict__ Bt) {
    int i = blockIdx.x * 256 + threadIdx.x;
    if (i >= 144 * 128) return;
    int c = i >> 7, k = i & 127;
    float v = 0.f;
    if (c < 128) {
        v = W1[k * 128 + c];
    } else if (c < 136) {
        int q = c - 128;
        const float* a = (q < 4) ? aS : aD;
        int h = q & 3;
        float s = 0.f;
        for (int j = 0; j < 32; ++j)
            s = fmaf(W1[k * 128 + h * 32 + j], a[h * 32 + j], s);
        v = s;
    }
    Bt[c * 128 + k] = f2bf(v);
}

// ---------------- layer 1 GEMM via MFMA: xp1(bf16), as1, ad1 ---------------
// block 256 = 4 waves x 16 rows; each wave: 16 rows x 144 cols (9 tiles).
__global__ __launch_bounds__(256) void gemm1_mfma(
        const float* __restrict__ x, const unsigned short* __restrict__ Bt,
        unsigned short* __restrict__ xpb, float* __restrict__ as1,
        float* __restrict__ ad1, int n) {
    int lane = threadIdx.x & 63;
    int wave = threadIdx.x >> 6;
    int rowbase = blockIdx.x * 64 + wave * 16;
    int arow = rowbase + (lane & 15);
    int lrow = (arow < n) ? arow : (n - 1);
    int ksub = (lane >> 4) * 4;

    f32x4 acc[9];
#pragma unroll
    for (int t = 0; t < 9; ++t) acc[t] = (f32x4){0.f, 0.f, 0.f, 0.f};

    const float* xr = x + (size_t)lrow * 128;
#pragma unroll
    for (int ks = 0; ks < 4; ++ks) {
        float4 c0 = *(const float4*)(xr + ks * 32 + ksub);
        float4 c1 = *(const float4*)(xr + ks * 32 + 16 + ksub);
        s16x8 a;
        a[0] = (short)f2bf(c0.x); a[1] = (short)f2bf(c0.y);
        a[2] = (short)f2bf(c0.z); a[3] = (short)f2bf(c0.w);
        a[4] = (short)f2bf(c1.x); a[5] = (short)f2bf(c1.y);
        a[6] = (short)f2bf(c1.z); a[7] = (short)f2bf(c1.w);
#pragma unroll
        for (int t = 0; t < 9; ++t) {
            const unsigned short* bp = Bt + (t * 16 + (lane & 15)) * 128 + ks * 32 + ksub;
            ushort4 b0 = *(const ushort4*)bp;
            ushort4 b1 = *(const ushort4*)(bp + 16);
            s16x8 b;
            b[0] = (short)b0.x; b[1] = (short)b0.y; b[2] = (short)b0.z; b[3] = (short)b0.w;
            b[4] = (short)b1.x; b[5] = (short)b1.y; b[6] = (short)b1.z; b[7] = (short)b1.w;
            acc[t] = __builtin_amdgcn_mfma_f32_16x16x32_bf16(a, b, acc[t], 0, 0, 0);
        }
    }

    int col = lane & 15;
    int crow = rowbase + (lane >> 4) * 4;
#pragma unroll
    for (int t = 0; t < 8; ++t) {
#pragma unroll
        for (int r = 0; r < 4; ++r) {
            int row = crow + r;
            if (row < n) xpb[(size_t)row * 128 + t * 16 + col] = f2bf(acc[t][r]);
        }
    }
    if (col < 8) {
#pragma unroll
        for (int r = 0; r < 4; ++r) {
            int row = crow + r;
            if (row < n) {
                if (col < 4) as1[row * 4 + col] = acc[8][r];
                else         ad1[row * 4 + (col - 4)] = acc[8][r];
            }
        }
    }
}

// ---------------- CSR build: histogram of dst ------------------------------
__global__ void hist_k(const void* ei, const int* dflag, int* cnt, int E, int Etot) {
    int i = blockIdx.x * blockDim.x + threadIdx.x;
    if (i >= Etot) return;
    bool i64 = (*dflag != 0);
    int d = (i < E) ? ldidx(ei, E + i, i64) : i - E;
    atomicAdd(&cnt[d], 1);
}

// ---------------- CSR build: single-block exclusive scan -------------------
__global__ void scan_k(const int* __restrict__ cnt, int* __restrict__ rp,
                       int* __restrict__ cur, int n) {
    __shared__ int part[1024];
    int t = threadIdx.x;
    int K = (n + 1023) / 1024;
    int lo = t * K;
    int hi = lo + K; if (hi > n) hi = n; if (lo > n) lo = n;
    int s = 0;
    for (int i = lo; i < hi; ++i) s += cnt[i];
    part[t] = s;
    __syncthreads();
    for (int off = 1; off < 1024; off <<= 1) {
        int v = (t >= off) ? part[t - off] : 0;
        __syncthreads();
        part[t] += v;
        __syncthreads();
    }
    int run = (t == 0) ? 0 : part[t - 1];
    for (int i = lo; i < hi; ++i) {
        rp[i] = run; cur[i] = run;
        run += cnt[i];
    }
    if (t == 1023) rp[n] = run;
}

// ---------------- CSR build: scatter src ids into position -----------------
__global__ void scatter_k(const void* ei, const int* dflag, int* cur,
                          int* src_csr, int E, int Etot) {
    int i = blockIdx.x * blockDim.x + threadIdx.x;
    if (i >= Etot) return;
    bool i64 = (*dflag != 0);
    int s, d;
    if (i < E) { s = ldidx(ei, i, i64); d = ldidx(ei, E + i, i64); }
    else       { s = d = i - E; }
    int pos = atomicAdd(&cur[d], 1);
    src_csr[pos] = s;
}

// ---------------- layer 1 aggregation: gather (bf16 xp), softmax, +b1, ELU -
// 32 lanes per dst node; lane holds channels [lane*4, lane*4+4); head = lane>>3.
__global__ void agg1(const int* __restrict__ rp, const int* __restrict__ src_csr,
                     const float* __restrict__ as1, const float* __restrict__ ad1,
                     const unsigned short* __restrict__ xpb, const float* __restrict__ b1,
                     float* __restrict__ hout, int n) {
    int g = blockIdx.x * 8 + (threadIdx.x >> 5);
    if (g >= n) return;
    int lane = threadIdx.x & 31;
    int h = lane >> 3;
    int beg = rp[g], end = rp[g + 1];
    float adv = ad1[g * 4 + h];
    float m = -INFINITY;
    for (int j = beg; j < end; ++j) {
        int s = src_csr[j];
        float e = as1[s * 4 + h] + adv;
        e = e > 0.f ? e : 0.2f * e;
        m = fmaxf(m, e);
    }
    float ax = 0.f, ay = 0.f, az = 0.f, aw = 0.f, den = 0.f;
    for (int j = beg; j < end; ++j) {
        int s = src_csr[j];
        float e = as1[s * 4 + h] + adv;
        e = e > 0.f ? e : 0.2f * e;
        float ex = expf(e - m);
        den += ex;
        uint2 v = *(const uint2*)(xpb + (size_t)s * 128 + lane * 4);
        ax = fmaf(bf2f(v.x & 0xFFFFu), ex, ax);
        ay = fmaf(bf2f(v.x >> 16),     ex, ay);
        az = fmaf(bf2f(v.y & 0xFFFFu), ex, az);
        aw = fmaf(bf2f(v.y >> 16),     ex, aw);
    }
    float inv = 1.f / den;
    int c0 = lane * 4;
    const float4 bb = *(const float4*)(b1 + c0);
    float o0 = fmaf(ax, inv, bb.x); o0 = o0 > 0.f ? o0 : expm1f(o0);
    float o1 = fmaf(ay, inv, bb.y); o1 = o1 > 0.f ? o1 : expm1f(o1);
    float o2 = fmaf(az, inv, bb.z); o2 = o2 > 0.f ? o2 : expm1f(o2);
    float o3 = fmaf(aw, inv, bb.w); o3 = o3 > 0.f ? o3 : expm1f(o3);
    float4 o = {o0, o1, o2, o3};
    *(float4*)(hout + (size_t)g * 128 + c0) = o;
}

// ---------------- layer 2 projection: xp2 = h @ W2, alpha_s2/alpha_d2 ------
__global__ void proj2(const float* __restrict__ h, const float* __restrict__ W2,
                      const float* __restrict__ aw_s, const float* __restrict__ aw_d,
                      float* __restrict__ xp2, float* __restrict__ as2,
                      float* __restrict__ ad2, int n) {
    __shared__ float hs[16][128];
    int t = threadIdx.x;
    int ln = t >> 4;
    int j = t & 15;
    int node = blockIdx.x * 16 + ln;
    if (node < n) {
#pragma unroll
        for (int q = 0; q < 8; ++q) {
            int c = j * 8 + q;
            hs[ln][c] = h[(size_t)node * 128 + c];
        }
    }
    __syncthreads();
    if (node >= n) return;
    float acc = 0.f;
#pragma unroll 4
    for (int c = 0; c < 128; ++c)
        acc = fmaf(hs[ln][c], W2[c * 16 + j], acc);
    xp2[(size_t)node * 16 + j] = acc;
    float ps = acc * aw_s[j];
    float pd = acc * aw_d[j];
    for (int off = 8; off >= 1; off >>= 1) {
        ps += __shfl_xor(ps, off, 16);
        pd += __shfl_xor(pd, off, 16);
    }
    if (j == 0) { as2[node] = ps; ad2[node] = pd; }
}

// ---------------- layer 2 aggregation + bias + log_softmax -----------------
__global__ void agg2(const int* __restrict__ rp, const int* __restrict__ src_csr,
                     const float* __restrict__ as2, const float* __restrict__ ad2,
                     const float* __restrict__ xp2, const float* __restrict__ b2,
                     float* __restrict__ out, int n) {
    int g = blockIdx.x * 64 + (threadIdx.x >> 2);
    if (g >= n) return;
    int lane = threadIdx.x & 3;
    int beg = rp[g], end = rp[g + 1];
    float adv = ad2[g];
    float m = -INFINITY;
    for (int j = beg; j < end; ++j) {
        float e = as2[src_csr[j]] + adv;
        e = e > 0.f ? e : 0.2f * e;
        m = fmaxf(m, e);
    }
    float ax = 0.f, ay = 0.f, az = 0.f, aw = 0.f, den = 0.f;
    for (int j = beg; j < end; ++j) {
        int s = src_csr[j];
        float e = as2[s] + adv;
        e = e > 0.f ? e : 0.2f * e;
        float ex = expf(e - m);
        den += ex;
        const float4 v = *(const float4*)(xp2 + (size_t)s * 16 + lane * 4);
        ax = fmaf(v.x, ex, ax); ay = fmaf(v.y, ex, ay);
        az = fmaf(v.z, ex, az); aw = fmaf(v.w, ex, aw);
    }
    float inv = 1.f / den;
    const float4 bb = *(const float4*)(b2 + lane * 4);
    float v0 = fmaf(ax, inv, bb.x);
    float v1 = fmaf(ay, inv, bb.y);
    float v2 = fmaf(az, inv, bb.z);
    float v3 = fmaf(aw, inv, bb.w);
    float mm = fmaxf(fmaxf(v0, v1), fmaxf(v2, v3));
    for (int off = 1; off < 4; off <<= 1) mm = fmaxf(mm, __shfl_xor(mm, off, 4));
    float ss = expf(v0 - mm) + expf(v1 - mm) + expf(v2 - mm) + expf(v3 - mm);
    for (int off = 1; off < 4; off <<= 1) ss += __shfl_xor(ss, off, 4);
    float ls = mm + logf(ss);
    float4 o = {v0 - ls, v1 - ls, v2 - ls, v3 - ls};
    *(float4*)(out + (size_t)g * 16 + lane * 4) = o;
}

// ---------------------------------------------------------------------------
extern "C" void kernel_launch(void* const* d_in, const int* in_sizes, int n_in,
                              void* d_out, int out_size, void* d_ws, size_t ws_size,
                              hipStream_t stream) {
    const float* x    = (const float*)d_in[0];
    const void*  ei   = d_in[1];
    const float* W1   = (const float*)d_in[2];
    const float* aS1  = (const float*)d_in[3];
    const float* aD1  = (const float*)d_in[4];
    const float* b1   = (const float*)d_in[5];
    const float* W2   = (const float*)d_in[6];
    const float* aS2  = (const float*)d_in[7];
    const float* aD2  = (const float*)d_in[8];
    const float* b2   = (const float*)d_in[9];

    const int N    = in_sizes[0] / 128;
    const int E    = in_sizes[1] / 2;
    const int Etot = E + N;

    // ---- workspace layout (byte-based) ----
    char* p = (char*)d_ws;
    unsigned short* xpb = (unsigned short*)p;  p += (size_t)128 * N * 2;
    float* as1 = (float*)p;                    p += (size_t)4 * N * 4;
    float* ad1 = (float*)p;                    p += (size_t)4 * N * 4;
    float* hbuf = (float*)p;                   p += (size_t)128 * N * 4;
    float* xp2 = (float*)p;                    p += (size_t)16 * N * 4;
    float* as2 = (float*)p;                    p += (size_t)N * 4;
    float* ad2 = (float*)p;                    p += (size_t)N * 4;
    int* cnt = (int*)p;                        p += (size_t)N * 4;
    int* rp = (int*)p;                         p += (size_t)(N + 1) * 4;
    int* cur = (int*)p;                        p += (size_t)N * 4;
    int* src_csr = (int*)p;                    p += (size_t)Etot * 4;
    unsigned short* Bt = (unsigned short*)p;   p += (size_t)144 * 128 * 2;
    int* dflag = (int*)p;

    hipMemsetAsync(cnt, 0, (size_t)N * sizeof(int), stream);

    detect_i64<<<1, 256, 0, stream>>>((const unsigned*)ei, dflag);

    prep_bt<<<72, 256, 0, stream>>>(W1, aS1, aD1, Bt);

    gemm1_mfma<<<(N + 63) / 64, 256, 0, stream>>>(x, Bt, xpb, as1, ad1, N);

    hist_k<<<(Etot + 255) / 256, 256, 0, stream>>>(ei, dflag, cnt, E, Etot);
    scan_k<<<1, 1024, 0, stream>>>(cnt, rp, cur, N);
    scatter_k<<<(Etot + 255) / 256, 256, 0, stream>>>(ei, dflag, cur, src_csr, E, Etot);

    agg1<<<(N + 7) / 8, 256, 0, stream>>>(rp, src_csr, as1, ad1, xpb, b1, hbuf, N);

    proj2<<<(N + 15) / 16, 256, 0, stream>>>(hbuf, W2, aS2, aD2, xp2, as2, ad2, N);

    agg2<<<(N + 63) / 64, 256, 0, stream>>>(rp, src_csr, as2, ad2, xp2, b2,
                                            (float*)d_out, N);
}

// Round 4
// 258.281 us; speedup vs baseline: 7.4869x; 1.4711x over previous
//
#include <hip/hip_runtime.h>
#include <math.h>

typedef __attribute__((ext_vector_type(4))) float f32x4;
typedef __attribute__((ext_vector_type(8))) short s16x8;

// ---------------- bf16 helpers ---------------------------------------------
__device__ __forceinline__ unsigned short f2bf(float f) {
    unsigned u = __float_as_uint(f);
    unsigned r = u + 0x7FFFu + ((u >> 16) & 1u);   // round-to-nearest-even
    return (unsigned short)(r >> 16);
}
__device__ __forceinline__ float bf2f(unsigned short b) {
    return __uint_as_float(((unsigned)b) << 16);
}

// Load an edge index that may be int32 or int64 (little-endian) -------------
__device__ __forceinline__ int ldidx(const void* ei, int pos, bool i64) {
    if (i64) return (int)((const long long*)ei)[pos];
    return ((const int*)ei)[pos];
}

// ---------------- dtype detection: int64 edge_index has zero high words -----
__global__ void detect_i64(const unsigned* ei32, int* flag) {
    __shared__ int nz;
    if (threadIdx.x == 0) nz = 0;
    __syncthreads();
    unsigned v = ei32[2 * threadIdx.x + 1];
    if (v != 0) atomicOr(&nz, 1);
    __syncthreads();
    if (threadIdx.x == 0) *flag = (nz == 0) ? 1 : 0;
}

// ---------------- prep: Bt[144][128] = [W1 | Ws | Wd]^T in bf16 ------------
__global__ void prep_bt(const float* __restrict__ W1, const float* __restrict__ aS,
                        const float* __restrict__ aD, unsigned short* __restrict__ Bt) {
    int i = blockIdx.x * 256 + threadIdx.x;
    if (i >= 144 * 128) return;
    int c = i >> 7, k = i & 127;
    float v = 0.f;
    if (c < 128) {
        v = W1[k * 128 + c];
    } else if (c < 136) {
        int q = c - 128;
        const float* a = (q < 4) ? aS : aD;
        int h = q & 3;
        float s = 0.f;
        for (int j = 0; j < 32; ++j)
            s = fmaf(W1[k * 128 + h * 32 + j], a[h * 32 + j], s);
        v = s;
    }
    Bt[c * 128 + k] = f2bf(v);
}

// ---------------- layer 1 GEMM via MFMA: xp1(bf16), as1, ad1 ---------------
__global__ __launch_bounds__(256) void gemm1_mfma(
        const float* __restrict__ x, const unsigned short* __restrict__ Bt,
        unsigned short* __restrict__ xpb, float* __restrict__ as1,
        float* __restrict__ ad1, int n) {
    int lane = threadIdx.x & 63;
    int wave = threadIdx.x >> 6;
    int rowbase = blockIdx.x * 64 + wave * 16;
    int arow = rowbase + (lane & 15);
    int lrow = (arow < n) ? arow : (n - 1);
    int ksub = (lane >> 4) * 4;

    f32x4 acc[9];
#pragma unroll
    for (int t = 0; t < 9; ++t) acc[t] = (f32x4){0.f, 0.f, 0.f, 0.f};

    const float* xr = x + (size_t)lrow * 128;
#pragma unroll
    for (int ks = 0; ks < 4; ++ks) {
        float4 c0 = *(const float4*)(xr + ks * 32 + ksub);
        float4 c1 = *(const float4*)(xr + ks * 32 + 16 + ksub);
        s16x8 a;
        a[0] = (short)f2bf(c0.x); a[1] = (short)f2bf(c0.y);
        a[2] = (short)f2bf(c0.z); a[3] = (short)f2bf(c0.w);
        a[4] = (short)f2bf(c1.x); a[5] = (short)f2bf(c1.y);
        a[6] = (short)f2bf(c1.z); a[7] = (short)f2bf(c1.w);
#pragma unroll
        for (int t = 0; t < 9; ++t) {
            const unsigned short* bp = Bt + (t * 16 + (lane & 15)) * 128 + ks * 32 + ksub;
            ushort4 b0 = *(const ushort4*)bp;
            ushort4 b1 = *(const ushort4*)(bp + 16);
            s16x8 b;
            b[0] = (short)b0.x; b[1] = (short)b0.y; b[2] = (short)b0.z; b[3] = (short)b0.w;
            b[4] = (short)b1.x; b[5] = (short)b1.y; b[6] = (short)b1.z; b[7] = (short)b1.w;
            acc[t] = __builtin_amdgcn_mfma_f32_16x16x32_bf16(a, b, acc[t], 0, 0, 0);
        }
    }

    int col = lane & 15;
    int crow = rowbase + (lane >> 4) * 4;
#pragma unroll
    for (int t = 0; t < 8; ++t) {
#pragma unroll
        for (int r = 0; r < 4; ++r) {
            int row = crow + r;
            if (row < n) xpb[(size_t)row * 128 + t * 16 + col] = f2bf(acc[t][r]);
        }
    }
    if (col < 8) {
#pragma unroll
        for (int r = 0; r < 4; ++r) {
            int row = crow + r;
            if (row < n) {
                if (col < 4) as1[row * 4 + col] = acc[8][r];
                else         ad1[row * 4 + (col - 4)] = acc[8][r];
            }
        }
    }
}

// ---------------- CSR build: histogram of dst ------------------------------
__global__ void hist_k(const void* ei, const int* dflag, int* cnt, int E, int Etot) {
    int i = blockIdx.x * blockDim.x + threadIdx.x;
    if (i >= Etot) return;
    bool i64 = (*dflag != 0);
    int d = (i < E) ? ldidx(ei, E + i, i64) : i - E;
    atomicAdd(&cnt[d], 1);
}

// ---------------- hierarchical scan: 1) per-block partial sums -------------
// block = 256 threads x 8 elems = 2048 per block.
__global__ void partial_k(const int* __restrict__ cnt, int* __restrict__ part, int n) {
    __shared__ int red[16];
    int t = threadIdx.x;
    int base = blockIdx.x * 2048 + t * 8;
    int s = 0;
    if (base + 8 <= n) {
        int4 a = *(const int4*)(cnt + base);
        int4 b = *(const int4*)(cnt + base + 4);
        s = a.x + a.y + a.z + a.w + b.x + b.y + b.z + b.w;
    } else {
        for (int i = base; i < n; ++i) s += cnt[i];
    }
    for (int off = 32; off >= 1; off >>= 1) s += __shfl_xor(s, off, 64);
    if ((t & 63) == 0) red[t >> 6] = s;
    __syncthreads();
    if (t == 0) {
        int tot = 0;
        for (int w = 0; w < (blockDim.x >> 6); ++w) tot += red[w];
        part[blockIdx.x] = tot;
    }
}

// ---------------- 2) tiny single-block scan of partials + rp[n] ------------
__global__ void scanp_k(int* __restrict__ part, int* __restrict__ rp, int B,
                        int n, int Etot) {
    __shared__ int ps[256];
    int t = threadIdx.x;
    ps[t] = (t < B) ? part[t] : 0;
    __syncthreads();
    for (int off = 1; off < 256; off <<= 1) {
        int v = (t >= off) ? ps[t - off] : 0;
        __syncthreads();
        ps[t] += v;
        __syncthreads();
    }
    if (t < B) part[t] = (t == 0) ? 0 : ps[t - 1];   // exclusive
    if (t == 0) rp[n] = Etot;
}

// ---------------- 3) per-block rescan: write rp and cur --------------------
__global__ void scan2_k(const int* __restrict__ cnt, const int* __restrict__ part,
                        int* __restrict__ rp, int* __restrict__ cur, int n) {
    __shared__ int ts[256];
    int t = threadIdx.x;
    int base = blockIdx.x * 2048 + t * 8;
    int local[8];
    int s = 0;
#pragma unroll
    for (int q = 0; q < 8; ++q) {
        int i = base + q;
        int v = (i < n) ? cnt[i] : 0;
        local[q] = s;          // exclusive within thread
        s += v;
    }
    ts[t] = s;
    __syncthreads();
    for (int off = 1; off < 256; off <<= 1) {
        int v = (t >= off) ? ts[t - off] : 0;
        __syncthreads();
        ts[t] += v;
        __syncthreads();
    }
    int pre = ((t == 0) ? 0 : ts[t - 1]) + part[blockIdx.x];
#pragma unroll
    for (int q = 0; q < 8; ++q) {
        int i = base + q;
        if (i < n) {
            int v = pre + local[q];
            rp[i] = v;
            cur[i] = v;
        }
    }
}

// ---------------- CSR build: scatter src ids into position -----------------
__global__ void scatter_k(const void* ei, const int* dflag, int* cur,
                          int* src_csr, int E, int Etot) {
    int i = blockIdx.x * blockDim.x + threadIdx.x;
    if (i >= Etot) return;
    bool i64 = (*dflag != 0);
    int s, d;
    if (i < E) { s = ldidx(ei, i, i64); d = ldidx(ei, E + i, i64); }
    else       { s = d = i - E; }
    int pos = atomicAdd(&cur[d], 1);
    src_csr[pos] = s;
}

// ---------------- layer 1 aggregation: single-pass online softmax ----------
// 32 lanes per dst node; lane holds channels [lane*4, lane*4+4); head = lane>>3.
__global__ void agg1(const int* __restrict__ rp, const int* __restrict__ src_csr,
                     const float* __restrict__ as1, const float* __restrict__ ad1,
                     const unsigned short* __restrict__ xpb, const float* __restrict__ b1,
                     float* __restrict__ hout, int n) {
    int g = blockIdx.x * 8 + (threadIdx.x >> 5);
    if (g >= n) return;
    int lane = threadIdx.x & 31;
    int h = lane >> 3;
    int beg = rp[g], end = rp[g + 1];
    float adv = ad1[g * 4 + h];
    float m = -INFINITY;
    float ax = 0.f, ay = 0.f, az = 0.f, aw = 0.f, den = 0.f;
    for (int j = beg; j < end; ++j) {
        int s = src_csr[j];
        float e = as1[s * 4 + h] + adv;
        e = e > 0.f ? e : 0.2f * e;
        float mn = fmaxf(m, e);
        float sc = expf(m - mn);     // 0 on first iter (m=-inf)
        float ex = expf(e - mn);
        uint2 v = *(const uint2*)(xpb + (size_t)s * 128 + lane * 4);
        den = fmaf(den, sc, ex);
        ax = fmaf(ax, sc, bf2f(v.x & 0xFFFFu) * ex);
        ay = fmaf(ay, sc, bf2f(v.x >> 16)     * ex);
        az = fmaf(az, sc, bf2f(v.y & 0xFFFFu) * ex);
        aw = fmaf(aw, sc, bf2f(v.y >> 16)     * ex);
        m = mn;
    }
    float inv = 1.f / den;
    int c0 = lane * 4;
    const float4 bb = *(const float4*)(b1 + c0);
    float o0 = fmaf(ax, inv, bb.x); o0 = o0 > 0.f ? o0 : expm1f(o0);
    float o1 = fmaf(ay, inv, bb.y); o1 = o1 > 0.f ? o1 : expm1f(o1);
    float o2 = fmaf(az, inv, bb.z); o2 = o2 > 0.f ? o2 : expm1f(o2);
    float o3 = fmaf(aw, inv, bb.w); o3 = o3 > 0.f ? o3 : expm1f(o3);
    float4 o = {o0, o1, o2, o3};
    *(float4*)(hout + (size_t)g * 128 + c0) = o;
}

// ---------------- layer 2 projection: xp2 = h @ W2, alpha_s2/alpha_d2 ------
__global__ void proj2(const float* __restrict__ h, const float* __restrict__ W2,
                      const float* __restrict__ aw_s, const float* __restrict__ aw_d,
                      float* __restrict__ xp2, float* __restrict__ as2,
                      float* __restrict__ ad2, int n) {
    __shared__ float hs[16][128];
    int t = threadIdx.x;
    int ln = t >> 4;
    int j = t & 15;
    int node = blockIdx.x * 16 + ln;
    if (node < n) {
#pragma unroll
        for (int q = 0; q < 8; ++q) {
            int c = j * 8 + q;
            hs[ln][c] = h[(size_t)node * 128 + c];
        }
    }
    __syncthreads();
    if (node >= n) return;
    float acc = 0.f;
#pragma unroll 4
    for (int c = 0; c < 128; ++c)
        acc = fmaf(hs[ln][c], W2[c * 16 + j], acc);
    xp2[(size_t)node * 16 + j] = acc;
    float ps = acc * aw_s[j];
    float pd = acc * aw_d[j];
    for (int off = 8; off >= 1; off >>= 1) {
        ps += __shfl_xor(ps, off, 16);
        pd += __shfl_xor(pd, off, 16);
    }
    if (j == 0) { as2[node] = ps; ad2[node] = pd; }
}

// ---------------- layer 2 aggregation + bias + log_softmax (online) --------
__global__ void agg2(const int* __restrict__ rp, const int* __restrict__ src_csr,
                     const float* __restrict__ as2, const float* __restrict__ ad2,
                     const float* __restrict__ xp2, const float* __restrict__ b2,
                     float* __restrict__ out, int n) {
    int g = blockIdx.x * 64 + (threadIdx.x >> 2);
    if (g >= n) return;
    int lane = threadIdx.x & 3;
    int beg = rp[g], end = rp[g + 1];
    float adv = ad2[g];
    float m = -INFINITY;
    float ax = 0.f, ay = 0.f, az = 0.f, aw = 0.f, den = 0.f;
    for (int j = beg; j < end; ++j) {
        int s = src_csr[j];
        float e = as2[s] + adv;
        e = e > 0.f ? e : 0.2f * e;
        float mn = fmaxf(m, e);
        float sc = expf(m - mn);
        float ex = expf(e - mn);
        const float4 v = *(const float4*)(xp2 + (size_t)s * 16 + lane * 4);
        den = fmaf(den, sc, ex);
        ax = fmaf(ax, sc, v.x * ex);
        ay = fmaf(ay, sc, v.y * ex);
        az = fmaf(az, sc, v.z * ex);
        aw = fmaf(aw, sc, v.w * ex);
        m = mn;
    }
    float inv = 1.f / den;
    const float4 bb = *(const float4*)(b2 + lane * 4);
    float v0 = fmaf(ax, inv, bb.x);
    float v1 = fmaf(ay, inv, bb.y);
    float v2 = fmaf(az, inv, bb.z);
    float v3 = fmaf(aw, inv, bb.w);
    float mm = fmaxf(fmaxf(v0, v1), fmaxf(v2, v3));
    for (int off = 1; off < 4; off <<= 1) mm = fmaxf(mm, __shfl_xor(mm, off, 4));
    float ss = expf(v0 - mm) + expf(v1 - mm) + expf(v2 - mm) + expf(v3 - mm);
    for (int off = 1; off < 4; off <<= 1) ss += __shfl_xor(ss, off, 4);
    float ls = mm + logf(ss);
    float4 o = {v0 - ls, v1 - ls, v2 - ls, v3 - ls};
    *(float4*)(out + (size_t)g * 16 + lane * 4) = o;
}

// ---------------------------------------------------------------------------
extern "C" void kernel_launch(void* const* d_in, const int* in_sizes, int n_in,
                              void* d_out, int out_size, void* d_ws, size_t ws_size,
                              hipStream_t stream) {
    const float* x    = (const float*)d_in[0];
    const void*  ei   = d_in[1];
    const float* W1   = (const float*)d_in[2];
    const float* aS1  = (const float*)d_in[3];
    const float* aD1  = (const float*)d_in[4];
    const float* b1   = (const float*)d_in[5];
    const float* W2   = (const float*)d_in[6];
    const float* aS2  = (const float*)d_in[7];
    const float* aD2  = (const float*)d_in[8];
    const float* b2   = (const float*)d_in[9];

    const int N    = in_sizes[0] / 128;
    const int E    = in_sizes[1] / 2;
    const int Etot = E + N;
    const int NB   = (N + 2047) / 2048;   // scan blocks (<=256)

    // ---- workspace layout (byte-based) ----
    char* p = (char*)d_ws;
    unsigned short* xpb = (unsigned short*)p;  p += (size_t)128 * N * 2;
    float* as1 = (float*)p;                    p += (size_t)4 * N * 4;
    float* ad1 = (float*)p;                    p += (size_t)4 * N * 4;
    float* hbuf = (float*)p;                   p += (size_t)128 * N * 4;
    float* xp2 = (float*)p;                    p += (size_t)16 * N * 4;
    float* as2 = (float*)p;                    p += (size_t)N * 4;
    float* ad2 = (float*)p;                    p += (size_t)N * 4;
    int* cnt = (int*)p;                        p += (size_t)N * 4;
    int* rp = (int*)p;                         p += (size_t)(N + 1) * 4;
    int* cur = (int*)p;                        p += (size_t)N * 4;
    int* src_csr = (int*)p;                    p += (size_t)Etot * 4;
    unsigned short* Bt = (unsigned short*)p;   p += (size_t)144 * 128 * 2;
    int* part = (int*)p;                       p += (size_t)256 * 4;
    int* dflag = (int*)p;

    hipMemsetAsync(cnt, 0, (size_t)N * sizeof(int), stream);

    detect_i64<<<1, 256, 0, stream>>>((const unsigned*)ei, dflag);

    prep_bt<<<72, 256, 0, stream>>>(W1, aS1, aD1, Bt);

    gemm1_mfma<<<(N + 63) / 64, 256, 0, stream>>>(x, Bt, xpb, as1, ad1, N);

    hist_k<<<(Etot + 255) / 256, 256, 0, stream>>>(ei, dflag, cnt, E, Etot);
    partial_k<<<NB, 256, 0, stream>>>(cnt, part, N);
    scanp_k<<<1, 256, 0, stream>>>(part, rp, NB, N, Etot);
    scan2_k<<<NB, 256, 0, stream>>>(cnt, part, rp, cur, N);
    scatter_k<<<(Etot + 255) / 256, 256, 0, stream>>>(ei, dflag, cur, src_csr, E, Etot);

    agg1<<<(N + 7) / 8, 256, 0, stream>>>(rp, src_csr, as1, ad1, xpb, b1, hbuf, N);

    proj2<<<(N + 15) / 16, 256, 0, stream>>>(hbuf, W2, aS2, aD2, xp2, as2, ad2, N);

    agg2<<<(N + 63) / 64, 256, 0, stream>>>(rp, src_csr, as2, ad2, xp2, b2,
                                            (float*)d_out, N);
}